// Round 1
// baseline (781.932 us; speedup 1.0000x reference)
//
#include <hip/hip_runtime.h>
#include <math.h>

#define D 128            // embed dim
#define TWO_D 256
#define WSTRIDE 260      // LDS stride (floats) for a W row: 256 + 4 pad, 16B-aligned
#define CSTRIDE 260      // LDS stride (floats) per staged cat vector

// ---------------------------------------------------------------------------
// Edge kernel: one wave (64 lanes) per edge.
//   attn = exp(dot(emb[row], emb[col]))
//   agg[row]  += attn * emb[col]   (atomic)
//   denom[row]+= attn              (atomic)
// ---------------------------------------------------------------------------
__global__ __launch_bounds__(256) void gcn_edge_attn(
    const float* __restrict__ emb,
    const int*   __restrict__ edges,   // [2][E] int32
    float*       __restrict__ agg,     // [N][128], zero-initialized
    float*       __restrict__ denom,   // [N], zero-initialized
    int E)
{
    int e    = (int)((blockIdx.x * 256u + threadIdx.x) >> 6);
    int lane = threadIdx.x & 63;
    if (e >= E) return;

    int row = edges[e];        // destination (segment id)
    int col = edges[E + e];    // source

    const float2 a = *(const float2*)(emb + (size_t)row * D + lane * 2);
    const float2 c = *(const float2*)(emb + (size_t)col * D + lane * 2);
    float s = a.x * c.x + a.y * c.y;
    #pragma unroll
    for (int off = 32; off >= 1; off >>= 1)
        s += __shfl_xor(s, off, 64);
    float attn = expf(s);

    float* dst = agg + (size_t)row * D + lane * 2;
    unsafeAtomicAdd(dst,     attn * c.x);
    unsafeAtomicAdd(dst + 1, attn * c.y);
    if (lane == 0)
        unsafeAtomicAdd(denom + row, attn);
}

// ---------------------------------------------------------------------------
// Node kernel (big-LDS variant): W staged once per block in LDS.
// Block = 256 threads = 4 waves. Each wave processes 4 nodes per pass.
// Lane l computes output features l and l+64 -> LN reduce is wave-internal.
// `out` holds unnormalized agg on entry; final result on exit (in-place safe:
// each node read + written by exactly one wave, ordered within the wave).
// LDS: W 128*260 floats + 4 waves * 4*260 floats = 149,760 B (dynamic).
// ---------------------------------------------------------------------------
__global__ __launch_bounds__(256) void gcn_node_lds(
    const float* __restrict__ emb,
    const float* __restrict__ W,       // [128][256] row-major
    const float* __restrict__ bias,
    const float* __restrict__ gamma,
    const float* __restrict__ beta,
    const float* __restrict__ denom,
    float*       __restrict__ out,     // agg in, result out
    int N)
{
    extern __shared__ float lds[];
    float* Wl = lds;                                  // [128][WSTRIDE]
    int tid  = threadIdx.x;
    int wave = tid >> 6;
    int lane = tid & 63;
    float* catw = lds + D * WSTRIDE + wave * 4 * CSTRIDE;  // this wave's 4 cat vecs

    // Stage W: 32768 floats, coalesced float4 loads, contiguous LDS writes.
    for (int i = tid * 4; i < D * TWO_D; i += 256 * 4) {
        int o = i >> 8;        // /256
        int k = i & 255;
        *(float4*)(Wl + o * WSTRIDE + k) = *(const float4*)(W + i);
    }
    __syncthreads();

    float bi0 = bias[lane],  bi1 = bias[lane + 64];
    float ga0 = gamma[lane], ga1 = gamma[lane + 64];
    float be0 = beta[lane],  be1 = beta[lane + 64];

    int gwave   = blockIdx.x * 4 + wave;              // global wave id
    int nwaves  = gridDim.x * 4;
    int nchunks = (N + 3) >> 2;

    for (int c = gwave; c < nchunks; c += nwaves) {
        int nb = c * 4;

        // ---- stage cat = [emb | agg/denom] for 4 nodes (wave-private LDS) ----
        #pragma unroll
        for (int r = 0; r < 2; ++r) {                 // emb halves: 512 floats
            int f = r * 256 + lane * 4;
            int j = f >> 7;
            int k = f & 127;
            int n = nb + j;
            float4 v = make_float4(0.f, 0.f, 0.f, 0.f);
            if (n < N) v = *(const float4*)(emb + (size_t)n * D + k);
            *(float4*)(catw + j * CSTRIDE + k) = v;
        }
        #pragma unroll
        for (int r = 0; r < 2; ++r) {                 // agg halves: 512 floats
            int f = r * 256 + lane * 4;
            int j = f >> 7;
            int k = f & 127;
            int n = nb + j;
            float4 v = make_float4(0.f, 0.f, 0.f, 0.f);
            if (n < N) {
                v = *(const float4*)(out + (size_t)n * D + k);
                float inv = 1.0f / (denom[n] + 1e-20f);
                v.x *= inv; v.y *= inv; v.z *= inv; v.w *= inv;
            }
            *(float4*)(catw + j * CSTRIDE + D + k) = v;
        }
        // DS pipe is in-order per wave: later ds_reads see these writes.

        // ---- matmul: acc[j][i] = x[nb+j][lane + 64*i] ----
        float accA[4] = {0.f, 0.f, 0.f, 0.f};
        float accB[4] = {0.f, 0.f, 0.f, 0.f};
        #pragma unroll 4
        for (int k = 0; k < TWO_D; k += 4) {
            float4 w0 = *(const float4*)(Wl + lane * WSTRIDE + k);
            float4 w1 = *(const float4*)(Wl + (lane + 64) * WSTRIDE + k);
            #pragma unroll
            for (int j = 0; j < 4; ++j) {
                float4 a = *(const float4*)(catw + j * CSTRIDE + k);  // broadcast
                accA[j] += w0.x * a.x + w0.y * a.y + w0.z * a.z + w0.w * a.w;
                accB[j] += w1.x * a.x + w1.y * a.y + w1.z * a.z + w1.w * a.w;
            }
        }

        // ---- bias + layernorm (reduction fully within this wave) ----
        #pragma unroll
        for (int j = 0; j < 4; ++j) {
            float x0 = accA[j] + bi0;
            float x1 = accB[j] + bi1;
            float s  = x0 + x1;
            float s2 = x0 * x0 + x1 * x1;
            #pragma unroll
            for (int off = 32; off >= 1; off >>= 1) {
                s  += __shfl_xor(s,  off, 64);
                s2 += __shfl_xor(s2, off, 64);
            }
            float mu  = s * (1.0f / 128.0f);
            float var = s2 * (1.0f / 128.0f) - mu * mu;
            float inv = rsqrtf(var + 1e-5f);
            int n = nb + j;
            if (n < N) {
                out[(size_t)n * D + lane]      = (x0 - mu) * inv * ga0 + be0;
                out[(size_t)n * D + lane + 64] = (x1 - mu) * inv * ga1 + be1;
            }
        }
    }
}

// ---------------------------------------------------------------------------
// Fallback node kernel (<=64KB LDS): W streamed from global (L2-resident).
// Block = 256 = 2 groups of 128 threads; one node per group.
// ---------------------------------------------------------------------------
__global__ __launch_bounds__(256) void gcn_node_fallback(
    const float* __restrict__ emb,
    const float* __restrict__ W,
    const float* __restrict__ bias,
    const float* __restrict__ gamma,
    const float* __restrict__ beta,
    const float* __restrict__ denom,
    float*       __restrict__ out,
    int N)
{
    __shared__ float scat[2][CSTRIDE];
    __shared__ float sred[2][4];
    int tid  = threadIdx.x;
    int g    = tid >> 7;
    int o    = tid & 127;
    int lane = tid & 63;
    int wig  = (tid >> 6) & 1;   // wave index within group

    for (int n0 = blockIdx.x * 2; n0 < N; n0 += gridDim.x * 2) {
        int n = n0 + g;
        bool act = (n < N);
        if (act) {
            float ev  = emb[(size_t)n * D + o];
            float inv = 1.0f / (denom[n] + 1e-20f);
            float av  = out[(size_t)n * D + o] * inv;
            scat[g][o]     = ev;
            scat[g][D + o] = av;
        }
        __syncthreads();
        float acc = 0.f;
        if (act) {
            const float4* wr = (const float4*)(W + (size_t)o * TWO_D);
            const float*  cv = scat[g];
            #pragma unroll 4
            for (int k4 = 0; k4 < TWO_D / 4; ++k4) {
                float4 w = wr[k4];
                float4 a = *(const float4*)(cv + k4 * 4);
                acc += w.x * a.x + w.y * a.y + w.z * a.z + w.w * a.w;
            }
            acc += bias[o];
        }
        float s = acc, s2 = acc * acc;
        #pragma unroll
        for (int off = 32; off >= 1; off >>= 1) {
            s  += __shfl_xor(s,  off, 64);
            s2 += __shfl_xor(s2, off, 64);
        }
        if (lane == 0) { sred[g][wig * 2] = s; sred[g][wig * 2 + 1] = s2; }
        __syncthreads();
        if (act) {
            float ts  = sred[g][0] + sred[g][2];
            float ts2 = sred[g][1] + sred[g][3];
            float mu  = ts * (1.0f / 128.0f);
            float var = ts2 * (1.0f / 128.0f) - mu * mu;
            float inv = rsqrtf(var + 1e-5f);
            out[(size_t)n * D + o] = (acc - mu) * inv * gamma[o] + beta[o];
        }
        __syncthreads();
    }
}

// ---------------------------------------------------------------------------
extern "C" void kernel_launch(void* const* d_in, const int* in_sizes, int n_in,
                              void* d_out, int out_size, void* d_ws, size_t ws_size,
                              hipStream_t stream) {
    const float* emb   = (const float*)d_in[0];
    const int*   edges = (const int*)  d_in[1];
    const float* W     = (const float*)d_in[2];
    const float* bias  = (const float*)d_in[3];
    const float* gamma = (const float*)d_in[4];
    const float* beta  = (const float*)d_in[5];
    float* out = (float*)d_out;

    int N = in_sizes[0] / D;        // 50000
    int E = in_sizes[1] / 2;        // 600000

    float* denom = (float*)d_ws;    // N floats

    // zero the accumulators (d_out doubles as agg scratch; d_ws holds denom)
    hipMemsetAsync(out,   0, (size_t)N * D * sizeof(float), stream);
    hipMemsetAsync(denom, 0, (size_t)N * sizeof(float), stream);

    // edge phase: one wave per edge
    int edgeBlocks = (E + 3) / 4;
    gcn_edge_attn<<<edgeBlocks, 256, 0, stream>>>(emb, edges, out, denom, E);

    // node phase: pick variant by per-WG LDS limit (queried at capture time)
    size_t ldsBytes = (size_t)(D * WSTRIDE + 4 * 4 * CSTRIDE) * sizeof(float); // 149,760
    int dev = 0;
    hipGetDevice(&dev);
    int maxShm = 0;
    hipDeviceGetAttribute(&maxShm, hipDeviceAttributeMaxSharedMemoryPerBlock, dev);

    if ((size_t)maxShm >= ldsBytes) {
        (void)hipFuncSetAttribute((const void*)gcn_node_lds,
                                  hipFuncAttributeMaxDynamicSharedMemorySize,
                                  (int)ldsBytes);   // defensive; no-op on AMD
        gcn_node_lds<<<256, 256, ldsBytes, stream>>>(
            emb, W, bias, gamma, beta, denom, out, N);
    } else {
        gcn_node_fallback<<<512, 256, 0, stream>>>(
            emb, W, bias, gamma, beta, denom, out, N);
    }
}

// Round 2
// 306.343 us; speedup vs baseline: 2.5525x; 2.5525x over previous
//
#include <hip/hip_runtime.h>
#include <math.h>

#define D 128
#define TWO_D 256
#define NB 12          // nodes per 128-thread group in node kernel (24/block-pass)
#define NODES_PER_PASS 24

// ============================ ws layout (bytes) =============================
#define OFF_DEG      0u
#define OFF_PART     200192u
#define OFF_BTOT     400384u
#define OFF_BTOTS    401408u
#define OFF_ROWSTART 402432u
#define OFF_CURSOR   602624u
#define OFF_COLIDX   802816u
#define OFF_WT4      3202816u
#define WS_NEEDED    3333888u

// ---------------------------------------------------------------------------
// CSR construction
// ---------------------------------------------------------------------------
__global__ __launch_bounds__(256) void k_hist(const int* __restrict__ edges,
                                              int* __restrict__ deg, int E) {
    int e = blockIdx.x * 256 + threadIdx.x;
    if (e < E) atomicAdd(&deg[edges[e]], 1);
}

// per-256-chunk exclusive scan; writes chunk-local exclusive scan + chunk total
__global__ __launch_bounds__(256) void k_scan1(const int* __restrict__ deg,
                                               int* __restrict__ part,
                                               int* __restrict__ btot, int N) {
    __shared__ int wsum[4];
    int t = threadIdx.x, b = blockIdx.x;
    int i = b * 256 + t;
    int v = (i < N) ? deg[i] : 0;
    int lane = t & 63, w = t >> 6;
    int s = v;
    #pragma unroll
    for (int d = 1; d <= 32; d <<= 1) {
        int u = __shfl_up(s, d, 64);
        if (lane >= d) s += u;
    }
    if (lane == 63) wsum[w] = s;
    __syncthreads();
    int wo = 0;
    for (int j = 0; j < w; ++j) wo += wsum[j];
    if (i < N) part[i] = wo + s - v;
    if (t == 255) btot[b] = wo + s;
}

// exclusive scan of the (<=256) chunk totals, one block
__global__ __launch_bounds__(256) void k_scan2(const int* __restrict__ btot,
                                               int* __restrict__ btots, int M) {
    __shared__ int wsum[4];
    int t = threadIdx.x;
    int v = (t < M) ? btot[t] : 0;
    int lane = t & 63, w = t >> 6;
    int s = v;
    #pragma unroll
    for (int d = 1; d <= 32; d <<= 1) {
        int u = __shfl_up(s, d, 64);
        if (lane >= d) s += u;
    }
    if (lane == 63) wsum[w] = s;
    __syncthreads();
    int wo = 0;
    for (int j = 0; j < w; ++j) wo += wsum[j];
    if (t < M) btots[t] = wo + s - v;
}

__global__ __launch_bounds__(256) void k_initcur(const int* __restrict__ part,
                                                 const int* __restrict__ btots,
                                                 int* __restrict__ rowstart,
                                                 int* __restrict__ cursor, int N) {
    int i = blockIdx.x * 256 + threadIdx.x;
    if (i < N) {
        int rs = part[i] + btots[i >> 8];
        rowstart[i] = rs;
        cursor[i]   = rs;
    }
}

__global__ __launch_bounds__(256) void k_scatter(const int* __restrict__ edges,
                                                 int* __restrict__ cursor,
                                                 int* __restrict__ colidx, int E) {
    int e = blockIdx.x * 256 + threadIdx.x;
    if (e < E) {
        int r = edges[e];
        int c = edges[E + e];
        int pos = atomicAdd(&cursor[r], 1);
        colidx[pos] = c;
    }
}

// ---------------------------------------------------------------------------
// Aggregation: one wave per destination node. No float atomics.
//   out[n] = ( sum_e exp(<emb[n],emb[col_e]>) * emb[col_e] ) / (sum_e exp + 1e-20)
// ---------------------------------------------------------------------------
__global__ __launch_bounds__(256) void gcn_agg(const float* __restrict__ emb,
                                               const int* __restrict__ colidx,
                                               const int* __restrict__ rowstart,
                                               const int* __restrict__ deg,
                                               float* __restrict__ out, int N) {
    int n    = blockIdx.x * 4 + (threadIdx.x >> 6);
    int lane = threadIdx.x & 63;
    if (n >= N) return;

    const float2 a = *(const float2*)(emb + (size_t)n * D + lane * 2);
    int e   = rowstart[n];
    int end = e + deg[n];

    float ax = 0.f, ay = 0.f, den = 0.f;
    // 2-edge unroll: two independent shfl-reduce chains for ILP
    for (; e + 1 < end; e += 2) {
        int c0 = colidx[e], c1 = colidx[e + 1];
        float2 v0 = *(const float2*)(emb + (size_t)c0 * D + lane * 2);
        float2 v1 = *(const float2*)(emb + (size_t)c1 * D + lane * 2);
        float t0 = a.x * v0.x + a.y * v0.y;
        float t1 = a.x * v1.x + a.y * v1.y;
        #pragma unroll
        for (int off = 32; off >= 1; off >>= 1) {
            t0 += __shfl_xor(t0, off, 64);
            t1 += __shfl_xor(t1, off, 64);
        }
        float w0 = expf(t0), w1 = expf(t1);
        ax  += w0 * v0.x + w1 * v1.x;
        ay  += w0 * v0.y + w1 * v1.y;
        den += w0 + w1;
    }
    if (e < end) {
        int c0 = colidx[e];
        float2 v0 = *(const float2*)(emb + (size_t)c0 * D + lane * 2);
        float t0 = a.x * v0.x + a.y * v0.y;
        #pragma unroll
        for (int off = 32; off >= 1; off >>= 1)
            t0 += __shfl_xor(t0, off, 64);
        float w0 = expf(t0);
        ax  += w0 * v0.x;
        ay  += w0 * v0.y;
        den += w0;
    }
    float inv = 1.0f / (den + 1e-20f);
    *(float2*)(out + (size_t)n * D + lane * 2) = make_float2(ax * inv, ay * inv);
}

// ---------------------------------------------------------------------------
// W pre-transpose into [k4][o][4] so node-kernel W loads are coalesced:
//   Wt4[(k4*128 + o)*4 + c] = W[o][k4*4 + c]
// ---------------------------------------------------------------------------
__global__ __launch_bounds__(256) void k_wt4(const float* __restrict__ W,
                                             float* __restrict__ Wt4) {
    int i = blockIdx.x * 256 + threadIdx.x;   // 32768 total
    if (i < D * TWO_D) {
        int c  = i & 3;
        int o  = (i >> 2) & 127;
        int k4 = i >> 9;
        Wt4[i] = W[o * TWO_D + k4 * 4 + c];
    }
}

// ---------------------------------------------------------------------------
// Node kernel: x = [emb | agg] @ W^T + b, then LayerNorm.
// Block 256 = 2 groups x 128 threads. Group g handles NB nodes per pass;
// thread computes feature o = t&127 for all NB nodes, holding W element in a
// register (12-node reuse -> W L2 traffic ~0.55 GB). cat staged in LDS,
// broadcast reads. agg is read in-place from `out` (already normalized).
// ---------------------------------------------------------------------------
__global__ __launch_bounds__(256) void gcn_node(const float* __restrict__ emb,
                                                const float* __restrict__ Wt4,
                                                const float* __restrict__ bias,
                                                const float* __restrict__ gamma,
                                                const float* __restrict__ beta,
                                                float* __restrict__ out, int N) {
    __shared__ float cat[NODES_PER_PASS][TWO_D];        // 24,576 B
    __shared__ float red[2][NB][2][2];                  // [grp][node][wave-half][s,s2]

    int t    = threadIdx.x;
    int g    = t >> 7;          // 0..1
    int o    = t & 127;
    int lane = t & 63;
    int wh   = (t >> 6) & 1;    // wave parity within group

    float bi = bias[o], gm = gamma[o], bt = beta[o];

    int npass = (N + NODES_PER_PASS - 1) / NODES_PER_PASS;
    for (int p = blockIdx.x; p < npass; p += gridDim.x) {
        int nb = p * NODES_PER_PASS;

        __syncthreads();   // protect cat/red from previous pass readers
        // stage cat = [emb | agg] for 24 nodes: 6144 floats, float4 coalesced
        for (int i = t * 4; i < NODES_PER_PASS * TWO_D; i += 256 * 4) {
            int j = i >> 8;
            int k = i & 255;
            int n = nb + j;
            float4 v = make_float4(0.f, 0.f, 0.f, 0.f);
            if (n < N)
                v = (k < D) ? *(const float4*)(emb + (size_t)n * D + k)
                            : *(const float4*)(out + (size_t)n * D + (k - D));
            *(float4*)(&cat[j][k]) = v;
        }
        __syncthreads();

        float acc[NB];
        #pragma unroll
        for (int j = 0; j < NB; ++j) acc[j] = 0.f;

        #pragma unroll 4
        for (int k4 = 0; k4 < TWO_D / 4; ++k4) {
            float4 w = *(const float4*)(Wt4 + (size_t)(k4 * 128 + o) * 4);
            #pragma unroll
            for (int j = 0; j < NB; ++j) {
                float4 c = *(const float4*)(&cat[g * NB + j][k4 * 4]);
                acc[j] += w.x * c.x + w.y * c.y + w.z * c.z + w.w * c.w;
            }
        }

        // per-node LayerNorm over 128 features (2 waves per group)
        #pragma unroll
        for (int j = 0; j < NB; ++j) {
            float x  = acc[j] + bi;
            float s  = x, s2 = x * x;
            #pragma unroll
            for (int off = 32; off >= 1; off >>= 1) {
                s  += __shfl_xor(s,  off, 64);
                s2 += __shfl_xor(s2, off, 64);
            }
            if (lane == 0) { red[g][j][wh][0] = s; red[g][j][wh][1] = s2; }
        }
        __syncthreads();
        #pragma unroll
        for (int j = 0; j < NB; ++j) {
            int n = nb + g * NB + j;
            if (n < N) {
                float s   = red[g][j][0][0] + red[g][j][1][0];
                float s2  = red[g][j][0][1] + red[g][j][1][1];
                float mu  = s * (1.0f / 128.0f);
                float var = s2 * (1.0f / 128.0f) - mu * mu;
                float inv = rsqrtf(var + 1e-5f);
                float x   = acc[j] + bi;
                out[(size_t)n * D + o] = (x - mu) * inv * gm + bt;
            }
        }
    }
}

// ===========================================================================
// Fallback path (round-1 kernels) in case ws_size < WS_NEEDED
// ===========================================================================
__global__ __launch_bounds__(256) void gcn_edge_attn(
    const float* __restrict__ emb, const int* __restrict__ edges,
    float* __restrict__ agg, float* __restrict__ denom, int E) {
    int e    = (int)((blockIdx.x * 256u + threadIdx.x) >> 6);
    int lane = threadIdx.x & 63;
    if (e >= E) return;
    int row = edges[e];
    int col = edges[E + e];
    const float2 a = *(const float2*)(emb + (size_t)row * D + lane * 2);
    const float2 c = *(const float2*)(emb + (size_t)col * D + lane * 2);
    float s = a.x * c.x + a.y * c.y;
    #pragma unroll
    for (int off = 32; off >= 1; off >>= 1) s += __shfl_xor(s, off, 64);
    float attn = expf(s);
    float* dst = agg + (size_t)row * D + lane * 2;
    unsafeAtomicAdd(dst,     attn * c.x);
    unsafeAtomicAdd(dst + 1, attn * c.y);
    if (lane == 0) unsafeAtomicAdd(denom + row, attn);
}

__global__ __launch_bounds__(256) void gcn_node_fallback(
    const float* __restrict__ emb, const float* __restrict__ W,
    const float* __restrict__ bias, const float* __restrict__ gamma,
    const float* __restrict__ beta, const float* __restrict__ denom,
    float* __restrict__ out, int N) {
    __shared__ float scat[2][TWO_D];
    __shared__ float sred[2][4];
    int tid  = threadIdx.x;
    int g    = tid >> 7;
    int o    = tid & 127;
    int lane = tid & 63;
    int wig  = (tid >> 6) & 1;
    for (int n0 = blockIdx.x * 2; n0 < N; n0 += gridDim.x * 2) {
        int n = n0 + g;
        bool act = (n < N);
        if (act) {
            float ev  = emb[(size_t)n * D + o];
            float inv = 1.0f / (denom[n] + 1e-20f);
            scat[g][o]     = ev;
            scat[g][D + o] = out[(size_t)n * D + o] * inv;
        }
        __syncthreads();
        float acc = 0.f;
        if (act) {
            const float4* wr = (const float4*)(W + (size_t)o * TWO_D);
            #pragma unroll 4
            for (int k4 = 0; k4 < TWO_D / 4; ++k4) {
                float4 w = wr[k4];
                float4 a = *(const float4*)(&scat[g][k4 * 4]);
                acc += w.x * a.x + w.y * a.y + w.z * a.z + w.w * a.w;
            }
            acc += bias[o];
        }
        float s = acc, s2 = acc * acc;
        #pragma unroll
        for (int off = 32; off >= 1; off >>= 1) {
            s  += __shfl_xor(s,  off, 64);
            s2 += __shfl_xor(s2, off, 64);
        }
        if (lane == 0) { sred[g][wig * 2] = s; sred[g][wig * 2 + 1] = s2; }
        __syncthreads();
        if (act) {
            float ts  = sred[g][0] + sred[g][2];
            float ts2 = sred[g][1] + sred[g][3];
            float mu  = ts * (1.0f / 128.0f);
            float var = ts2 * (1.0f / 128.0f) - mu * mu;
            float inv = rsqrtf(var + 1e-5f);
            out[(size_t)n * D + o] = (acc - mu) * inv * gamma[o] + beta[o];
        }
        __syncthreads();
    }
}

// ---------------------------------------------------------------------------
extern "C" void kernel_launch(void* const* d_in, const int* in_sizes, int n_in,
                              void* d_out, int out_size, void* d_ws, size_t ws_size,
                              hipStream_t stream) {
    const float* emb   = (const float*)d_in[0];
    const int*   edges = (const int*)  d_in[1];
    const float* W     = (const float*)d_in[2];
    const float* bias  = (const float*)d_in[3];
    const float* gamma = (const float*)d_in[4];
    const float* beta  = (const float*)d_in[5];
    float* out = (float*)d_out;

    int N = in_sizes[0] / D;        // 50000
    int E = in_sizes[1] / 2;        // 600000

    if (ws_size >= (size_t)WS_NEEDED) {
        char* ws = (char*)d_ws;
        int* deg      = (int*)  (ws + OFF_DEG);
        int* part     = (int*)  (ws + OFF_PART);
        int* btot     = (int*)  (ws + OFF_BTOT);
        int* btots    = (int*)  (ws + OFF_BTOTS);
        int* rowstart = (int*)  (ws + OFF_ROWSTART);
        int* cursor   = (int*)  (ws + OFF_CURSOR);
        int* colidx   = (int*)  (ws + OFF_COLIDX);
        float* Wt4    = (float*)(ws + OFF_WT4);

        int eBlocks = (E + 255) / 256;
        int nBlocks = (N + 255) / 256;   // 196

        hipMemsetAsync(deg, 0, (size_t)N * sizeof(int), stream);
        k_wt4    <<<(D * TWO_D + 255) / 256, 256, 0, stream>>>(W, Wt4);
        k_hist   <<<eBlocks, 256, 0, stream>>>(edges, deg, E);
        k_scan1  <<<nBlocks, 256, 0, stream>>>(deg, part, btot, N);
        k_scan2  <<<1,       256, 0, stream>>>(btot, btots, nBlocks);
        k_initcur<<<nBlocks, 256, 0, stream>>>(part, btots, rowstart, cursor, N);
        k_scatter<<<eBlocks, 256, 0, stream>>>(edges, cursor, colidx, E);
        gcn_agg  <<<(N + 3) / 4, 256, 0, stream>>>(emb, colidx, rowstart, deg, out, N);
        gcn_node <<<1024, 256, 0, stream>>>(emb, Wt4, bias, gamma, beta, out, N);
    } else {
        // fallback: round-1 atomic path (needs only N floats of ws)
        float* denom = (float*)d_ws;
        hipMemsetAsync(out,   0, (size_t)N * D * sizeof(float), stream);
        hipMemsetAsync(denom, 0, (size_t)N * sizeof(float), stream);
        gcn_edge_attn<<<(E + 3) / 4, 256, 0, stream>>>(emb, edges, out, denom, E);
        gcn_node_fallback<<<512, 256, 0, stream>>>(emb, W, bias, gamma, beta,
                                                   denom, out, N);
    }
}

// Round 3
// 236.343 us; speedup vs baseline: 3.3085x; 1.2962x over previous
//
#include <hip/hip_runtime.h>
#include <math.h>

#define D 128
#define TWO_D 256

typedef __bf16 v8bf __attribute__((ext_vector_type(8)));
typedef float  v4f  __attribute__((ext_vector_type(4)));

// ============================ ws layout (bytes) =============================
#define OFF_DEG      0u
#define OFF_PART     200192u
#define OFF_BTOT     400384u
#define OFF_BTOTS    401408u
#define OFF_ROWSTART 402432u
#define OFF_CURSOR   602624u
#define OFF_COLIDX   802816u
#define OFF_WBF16    3202816u
#define WS_NEEDED    3268352u

// ---------------------------------------------------------------------------
// CSR construction
// ---------------------------------------------------------------------------
__global__ __launch_bounds__(256) void k_hist(const int* __restrict__ edges,
                                              int* __restrict__ deg, int E) {
    int e = blockIdx.x * 256 + threadIdx.x;
    if (e < E) atomicAdd(&deg[edges[e]], 1);
}

__global__ __launch_bounds__(256) void k_scan1(const int* __restrict__ deg,
                                               int* __restrict__ part,
                                               int* __restrict__ btot, int N) {
    __shared__ int wsum[4];
    int t = threadIdx.x, b = blockIdx.x;
    int i = b * 256 + t;
    int v = (i < N) ? deg[i] : 0;
    int lane = t & 63, w = t >> 6;
    int s = v;
    #pragma unroll
    for (int d = 1; d <= 32; d <<= 1) {
        int u = __shfl_up(s, d, 64);
        if (lane >= d) s += u;
    }
    if (lane == 63) wsum[w] = s;
    __syncthreads();
    int wo = 0;
    for (int j = 0; j < w; ++j) wo += wsum[j];
    if (i < N) part[i] = wo + s - v;
    if (t == 255) btot[b] = wo + s;
}

__global__ __launch_bounds__(256) void k_scan2(const int* __restrict__ btot,
                                               int* __restrict__ btots, int M) {
    __shared__ int wsum[4];
    int t = threadIdx.x;
    int v = (t < M) ? btot[t] : 0;
    int lane = t & 63, w = t >> 6;
    int s = v;
    #pragma unroll
    for (int d = 1; d <= 32; d <<= 1) {
        int u = __shfl_up(s, d, 64);
        if (lane >= d) s += u;
    }
    if (lane == 63) wsum[w] = s;
    __syncthreads();
    int wo = 0;
    for (int j = 0; j < w; ++j) wo += wsum[j];
    if (t < M) btots[t] = wo + s - v;
}

__global__ __launch_bounds__(256) void k_initcur(const int* __restrict__ part,
                                                 const int* __restrict__ btots,
                                                 int* __restrict__ rowstart,
                                                 int* __restrict__ cursor, int N) {
    int i = blockIdx.x * 256 + threadIdx.x;
    if (i < N) {
        int rs = part[i] + btots[i >> 8];
        rowstart[i] = rs;
        cursor[i]   = rs;
    }
}

__global__ __launch_bounds__(256) void k_scatter(const int* __restrict__ edges,
                                                 int* __restrict__ cursor,
                                                 int* __restrict__ colidx, int E) {
    int e = blockIdx.x * 256 + threadIdx.x;
    if (e < E) {
        int r = edges[e];
        int c = edges[E + e];
        int pos = atomicAdd(&cursor[r], 1);
        colidx[pos] = c;
    }
}

// ---------------------------------------------------------------------------
// W fp32 [128][256] -> bf16 same layout
// ---------------------------------------------------------------------------
__global__ __launch_bounds__(256) void k_wcvt(const float* __restrict__ W,
                                              __bf16* __restrict__ Wb) {
    int i = blockIdx.x * 256 + threadIdx.x;
    if (i < D * TWO_D) Wb[i] = (__bf16)W[i];
}

// ---------------------------------------------------------------------------
// Aggregation: HALF-wave (32 lanes, float4 = 128 dims) per destination node.
//   out[n] = ( sum_e exp(<emb[n],emb[col]>) * emb[col] ) / (sum_e exp + 1e-20)
// 5-step width-32 butterfly; both halves of a wave run independent nodes.
// ---------------------------------------------------------------------------
__global__ __launch_bounds__(256) void gcn_agg(const float* __restrict__ emb,
                                               const int* __restrict__ colidx,
                                               const int* __restrict__ rowstart,
                                               const int* __restrict__ deg,
                                               float* __restrict__ out, int N) {
    int n = blockIdx.x * 8 + (threadIdx.x >> 5);
    int l = threadIdx.x & 31;
    if (n >= N) return;

    const float4 a = *(const float4*)(emb + (size_t)n * D + l * 4);
    int e   = rowstart[n];
    int end = e + deg[n];

    float sx = 0.f, sy = 0.f, sz = 0.f, sw = 0.f, den = 0.f;
    for (; e + 1 < end; e += 2) {
        int c0 = colidx[e], c1 = colidx[e + 1];
        float4 v0 = *(const float4*)(emb + (size_t)c0 * D + l * 4);
        float4 v1 = *(const float4*)(emb + (size_t)c1 * D + l * 4);
        float t0 = a.x * v0.x + a.y * v0.y + a.z * v0.z + a.w * v0.w;
        float t1 = a.x * v1.x + a.y * v1.y + a.z * v1.z + a.w * v1.w;
        #pragma unroll
        for (int off = 16; off >= 1; off >>= 1) {
            t0 += __shfl_xor(t0, off, 32);
            t1 += __shfl_xor(t1, off, 32);
        }
        float w0 = __expf(t0), w1 = __expf(t1);
        sx += w0 * v0.x + w1 * v1.x;
        sy += w0 * v0.y + w1 * v1.y;
        sz += w0 * v0.z + w1 * v1.z;
        sw += w0 * v0.w + w1 * v1.w;
        den += w0 + w1;
    }
    if (e < end) {
        int c0 = colidx[e];
        float4 v0 = *(const float4*)(emb + (size_t)c0 * D + l * 4);
        float t0 = a.x * v0.x + a.y * v0.y + a.z * v0.z + a.w * v0.w;
        #pragma unroll
        for (int off = 16; off >= 1; off >>= 1)
            t0 += __shfl_xor(t0, off, 32);
        float w0 = __expf(t0);
        sx += w0 * v0.x; sy += w0 * v0.y; sz += w0 * v0.z; sw += w0 * v0.w;
        den += w0;
    }
    float inv = 1.0f / (den + 1e-20f);
    *(float4*)(out + (size_t)n * D + l * 4) =
        make_float4(sx * inv, sy * inv, sz * inv, sw * inv);
}

// ---------------------------------------------------------------------------
// Node kernel (MFMA): x = [emb | agg] @ W^T + b, then LayerNorm.
// Block = 256 = 4 waves; block covers 64 nodes (wave w -> rows w*16..w*16+15).
// A = x tile (bf16, converted during LDS staging, XOR-swizzled 16B granules:
//   granule(m, g) stored at m*32 + (g ^ (m&7)) -> perfect ds_read_b128 banks).
// B = Wb from global ([feat][k] row-major: lane n=feat reads 8 consecutive k).
// D tile: col=lane&15 (feat), row=quad*4+reg (node)  [m89/m91-verified].
// LN over features = 4-step shfl_xor(1,2,4,8) within the wave. In-place on
// `out` (agg read during staging of this block's own rows, then overwritten).
// ---------------------------------------------------------------------------
__global__ __launch_bounds__(256) void gcn_node_mfma(
    const float* __restrict__ emb,
    const __bf16* __restrict__ Wb,
    const float* __restrict__ bias,
    const float* __restrict__ gamma,
    const float* __restrict__ beta,
    float* __restrict__ out, int N)
{
    __shared__ __align__(16) __bf16 xt[64 * 256];   // 32 KB swizzled x-tile

    int t    = threadIdx.x;
    int wave = t >> 6;
    int lane = t & 63;
    int n0   = blockIdx.x * 64;

    // ---- stage: 64 rows x 32 granules (16B = 8 elems), fp32 -> bf16 ----
    #pragma unroll
    for (int j = 0; j < 8; ++j) {
        int gf = j * 256 + t;          // granule flat id 0..2047
        int m  = gf >> 5;              // local row
        int g  = gf & 31;              // granule within row
        int n  = n0 + m;
        int k  = g * 8;
        v8bf v;
        if (n < N) {
            const float* src = (k < D) ? (emb + (size_t)n * D + k)
                                       : (out + (size_t)n * D + (k - D));
            float4 f0 = *(const float4*)(src);
            float4 f1 = *(const float4*)(src + 4);
            v[0] = (__bf16)f0.x; v[1] = (__bf16)f0.y;
            v[2] = (__bf16)f0.z; v[3] = (__bf16)f0.w;
            v[4] = (__bf16)f1.x; v[5] = (__bf16)f1.y;
            v[6] = (__bf16)f1.z; v[7] = (__bf16)f1.w;
        } else {
            #pragma unroll
            for (int q = 0; q < 8; ++q) v[q] = (__bf16)0.0f;
        }
        int gidx = m * 32 + (g ^ (m & 7));
        *(v8bf*)(xt + gidx * 8) = v;
    }
    __syncthreads();

    int mrow = lane & 15;              // A row / D col selector
    int quad = lane >> 4;
    int mloc = wave * 16 + mrow;       // local node row 0..63

    // A fragments: one per kt (K = 256 = 8 x 32)
    v8bf a[8];
    #pragma unroll
    for (int kt = 0; kt < 8; ++kt) {
        int g = (kt * 4 + quad) ^ (mloc & 7);
        a[kt] = *(const v8bf*)(xt + (mloc * 32 + g) * 8);
    }

    // epilogue constants for this lane's 8 feature columns
    float bi[8], gm[8], bt[8];
    #pragma unroll
    for (int ft = 0; ft < 8; ++ft) {
        int f = ft * 16 + mrow;
        bi[ft] = bias[f]; gm[ft] = gamma[f]; bt[ft] = beta[f];
    }

    v4f acc[8];
    #pragma unroll
    for (int ft = 0; ft < 8; ++ft)
        #pragma unroll
        for (int r = 0; r < 4; ++r) acc[ft][r] = 0.0f;

    // kt outer / ft inner: 8 independent accumulator chains
    #pragma unroll
    for (int kt = 0; kt < 8; ++kt) {
        #pragma unroll
        for (int ft = 0; ft < 8; ++ft) {
            v8bf b = *(const v8bf*)(Wb + (ft * 16 + mrow) * TWO_D + kt * 32 + quad * 8);
            acc[ft] = __builtin_amdgcn_mfma_f32_16x16x32_bf16(a[kt], b, acc[ft], 0, 0, 0);
        }
    }

    // bias
    #pragma unroll
    for (int ft = 0; ft < 8; ++ft)
        #pragma unroll
        for (int r = 0; r < 4; ++r) acc[ft][r] += bi[ft];

    // LayerNorm per node row (row = quad*4 + r), reduce over 128 feats
    #pragma unroll
    for (int r = 0; r < 4; ++r) {
        float s = 0.f, s2 = 0.f;
        #pragma unroll
        for (int ft = 0; ft < 8; ++ft) {
            float x = acc[ft][r];
            s += x; s2 += x * x;
        }
        #pragma unroll
        for (int off = 1; off <= 8; off <<= 1) {
            s  += __shfl_xor(s,  off, 64);
            s2 += __shfl_xor(s2, off, 64);
        }
        float mu  = s * (1.0f / 128.0f);
        float var = s2 * (1.0f / 128.0f) - mu * mu;
        float inv = rsqrtf(var + 1e-5f);
        int n = n0 + wave * 16 + quad * 4 + r;
        if (n < N) {
            #pragma unroll
            for (int ft = 0; ft < 8; ++ft) {
                int f = ft * 16 + mrow;
                out[(size_t)n * D + f] = (acc[ft][r] - mu) * inv * gm[ft] + bt[ft];
            }
        }
    }
}

// ===========================================================================
// Fallback path (round-1 kernels) in case ws_size < WS_NEEDED
// ===========================================================================
__global__ __launch_bounds__(256) void gcn_edge_attn(
    const float* __restrict__ emb, const int* __restrict__ edges,
    float* __restrict__ agg, float* __restrict__ denom, int E) {
    int e    = (int)((blockIdx.x * 256u + threadIdx.x) >> 6);
    int lane = threadIdx.x & 63;
    if (e >= E) return;
    int row = edges[e];
    int col = edges[E + e];
    const float2 a = *(const float2*)(emb + (size_t)row * D + lane * 2);
    const float2 c = *(const float2*)(emb + (size_t)col * D + lane * 2);
    float s = a.x * c.x + a.y * c.y;
    #pragma unroll
    for (int off = 32; off >= 1; off >>= 1) s += __shfl_xor(s, off, 64);
    float attn = expf(s);
    float* dst = agg + (size_t)row * D + lane * 2;
    unsafeAtomicAdd(dst,     attn * c.x);
    unsafeAtomicAdd(dst + 1, attn * c.y);
    if (lane == 0) unsafeAtomicAdd(denom + row, attn);
}

__global__ __launch_bounds__(256) void gcn_node_fallback(
    const float* __restrict__ emb, const float* __restrict__ W,
    const float* __restrict__ bias, const float* __restrict__ gamma,
    const float* __restrict__ beta, const float* __restrict__ denom,
    float* __restrict__ out, int N) {
    __shared__ float scat[2][TWO_D];
    __shared__ float sred[2][4];
    int tid  = threadIdx.x;
    int g    = tid >> 7;
    int o    = tid & 127;
    int lane = tid & 63;
    int wig  = (tid >> 6) & 1;
    for (int n0 = blockIdx.x * 2; n0 < N; n0 += gridDim.x * 2) {
        int n = n0 + g;
        bool act = (n < N);
        if (act) {
            float ev  = emb[(size_t)n * D + o];
            float inv = 1.0f / (denom[n] + 1e-20f);
            scat[g][o]     = ev;
            scat[g][D + o] = out[(size_t)n * D + o] * inv;
        }
        __syncthreads();
        float acc = 0.f;
        if (act) {
            const float4* wr = (const float4*)(W + (size_t)o * TWO_D);
            #pragma unroll 4
            for (int k4 = 0; k4 < TWO_D / 4; ++k4) {
                float4 w = wr[k4];
                float4 a = *(const float4*)(&scat[g][k4 * 4]);
                acc += w.x * a.x + w.y * a.y + w.z * a.z + w.w * a.w;
            }
            acc += bias[o];
        }
        float s = acc, s2 = acc * acc;
        #pragma unroll
        for (int off = 32; off >= 1; off >>= 1) {
            s  += __shfl_xor(s,  off, 64);
            s2 += __shfl_xor(s2, off, 64);
        }
        if (lane == 0) { sred[g][wig * 2] = s; sred[g][wig * 2 + 1] = s2; }
        __syncthreads();
        if (act) {
            float ts  = sred[g][0] + sred[g][2];
            float ts2 = sred[g][1] + sred[g][3];
            float mu  = ts * (1.0f / 128.0f);
            float var = ts2 * (1.0f / 128.0f) - mu * mu;
            float inv = rsqrtf(var + 1e-5f);
            out[(size_t)n * D + o] = (acc - mu) * inv * gamma[o] + beta[o];
        }
        __syncthreads();
    }
}

// ---------------------------------------------------------------------------
extern "C" void kernel_launch(void* const* d_in, const int* in_sizes, int n_in,
                              void* d_out, int out_size, void* d_ws, size_t ws_size,
                              hipStream_t stream) {
    const float* emb   = (const float*)d_in[0];
    const int*   edges = (const int*)  d_in[1];
    const float* W     = (const float*)d_in[2];
    const float* bias  = (const float*)d_in[3];
    const float* gamma = (const float*)d_in[4];
    const float* beta  = (const float*)d_in[5];
    float* out = (float*)d_out;

    int N = in_sizes[0] / D;        // 50000
    int E = in_sizes[1] / 2;        // 600000
    int nBlocks = (N + 255) / 256;  // 196 (scan2 requires <=256)

    if (ws_size >= (size_t)WS_NEEDED && nBlocks <= 256) {
        char* ws = (char*)d_ws;
        int*    deg      = (int*)   (ws + OFF_DEG);
        int*    part     = (int*)   (ws + OFF_PART);
        int*    btot     = (int*)   (ws + OFF_BTOT);
        int*    btots    = (int*)   (ws + OFF_BTOTS);
        int*    rowstart = (int*)   (ws + OFF_ROWSTART);
        int*    cursor   = (int*)   (ws + OFF_CURSOR);
        int*    colidx   = (int*)   (ws + OFF_COLIDX);
        __bf16* Wb       = (__bf16*)(ws + OFF_WBF16);

        int eBlocks = (E + 255) / 256;

        hipMemsetAsync(deg, 0, (size_t)N * sizeof(int), stream);
        k_wcvt   <<<(D * TWO_D + 255) / 256, 256, 0, stream>>>(W, Wb);
        k_hist   <<<eBlocks, 256, 0, stream>>>(edges, deg, E);
        k_scan1  <<<nBlocks, 256, 0, stream>>>(deg, part, btot, N);
        k_scan2  <<<1,       256, 0, stream>>>(btot, btots, nBlocks);
        k_initcur<<<nBlocks, 256, 0, stream>>>(part, btots, rowstart, cursor, N);
        k_scatter<<<eBlocks, 256, 0, stream>>>(edges, cursor, colidx, E);
        gcn_agg  <<<(N + 7) / 8, 256, 0, stream>>>(emb, colidx, rowstart, deg, out, N);
        gcn_node_mfma<<<(N + 63) / 64, 256, 0, stream>>>(emb, Wb, bias, gamma,
                                                         beta, out, N);
    } else {
        float* denom = (float*)d_ws;
        hipMemsetAsync(out,   0, (size_t)N * D * sizeof(float), stream);
        hipMemsetAsync(denom, 0, (size_t)N * sizeof(float), stream);
        gcn_edge_attn<<<(E + 3) / 4, 256, 0, stream>>>(emb, edges, out, denom, E);
        gcn_node_fallback<<<512, 256, 0, stream>>>(emb, W, bias, gamma, beta,
                                                   denom, out, N);
    }
}

// Round 4
// 219.906 us; speedup vs baseline: 3.5558x; 1.0747x over previous
//
#include <hip/hip_runtime.h>
#include <math.h>

#define D 128
#define TWO_D 256

typedef __bf16 v8bf __attribute__((ext_vector_type(8)));
typedef float  v4f  __attribute__((ext_vector_type(4)));

// ============================ ws layout (bytes) =============================
#define OFF_DEG      0u
#define OFF_PART     200192u
#define OFF_BTOT     400384u
#define OFF_BTOTS    401408u
#define OFF_ROWSTART 402432u
#define OFF_CURSOR   602624u
#define OFF_COLIDX   802816u
#define OFF_WBF16    3203072u
#define OFF_EMBB     3268608u
#define WS_TIER_B    3268608u     // CSR + Wb only (round-3 path)
#define WS_TIER_A    16068608u    // + embb (N*128 bf16)

// ---------------------------------------------------------------------------
// CSR construction
// ---------------------------------------------------------------------------
__global__ __launch_bounds__(256) void k_hist(const int* __restrict__ edges,
                                              int* __restrict__ deg, int E) {
    int e = blockIdx.x * 256 + threadIdx.x;
    if (e < E) atomicAdd(&deg[edges[e]], 1);
}

__global__ __launch_bounds__(256) void k_scan1(const int* __restrict__ deg,
                                               int* __restrict__ part,
                                               int* __restrict__ btot, int N) {
    __shared__ int wsum[4];
    int t = threadIdx.x, b = blockIdx.x;
    int i = b * 256 + t;
    int v = (i < N) ? deg[i] : 0;
    int lane = t & 63, w = t >> 6;
    int s = v;
    #pragma unroll
    for (int d = 1; d <= 32; d <<= 1) {
        int u = __shfl_up(s, d, 64);
        if (lane >= d) s += u;
    }
    if (lane == 63) wsum[w] = s;
    __syncthreads();
    int wo = 0;
    for (int j = 0; j < w; ++j) wo += wsum[j];
    if (i < N) part[i] = wo + s - v;
    if (t == 255) btot[b] = wo + s;
}

__global__ __launch_bounds__(256) void k_scan2(const int* __restrict__ btot,
                                               int* __restrict__ btots, int M) {
    __shared__ int wsum[4];
    int t = threadIdx.x;
    int v = (t < M) ? btot[t] : 0;
    int lane = t & 63, w = t >> 6;
    int s = v;
    #pragma unroll
    for (int d = 1; d <= 32; d <<= 1) {
        int u = __shfl_up(s, d, 64);
        if (lane >= d) s += u;
    }
    if (lane == 63) wsum[w] = s;
    __syncthreads();
    int wo = 0;
    for (int j = 0; j < w; ++j) wo += wsum[j];
    if (t < M) btots[t] = wo + s - v;
}

__global__ __launch_bounds__(256) void k_initcur(const int* __restrict__ part,
                                                 const int* __restrict__ btots,
                                                 int* __restrict__ rowstart,
                                                 int* __restrict__ cursor, int N) {
    int i = blockIdx.x * 256 + threadIdx.x;
    if (i < N) {
        int rs = part[i] + btots[i >> 8];
        rowstart[i] = rs;
        cursor[i]   = rs;
    }
}

__global__ __launch_bounds__(256) void k_scatter(const int* __restrict__ edges,
                                                 int* __restrict__ cursor,
                                                 int* __restrict__ colidx, int E) {
    int e = blockIdx.x * 256 + threadIdx.x;
    if (e < E) {
        int r = edges[e];
        int c = edges[E + e];
        int pos = atomicAdd(&cursor[r], 1);
        colidx[pos] = c;
    }
}

// ---------------------------------------------------------------------------
// Combined fp32->bf16 conversion: emb (nEmb elems) then W (D*TWO_D elems).
// Each thread converts 8 elements.
// ---------------------------------------------------------------------------
__global__ __launch_bounds__(256) void k_cvt(const float* __restrict__ emb,
                                             const float* __restrict__ W,
                                             __bf16* __restrict__ embb,
                                             __bf16* __restrict__ Wb, int nEmb) {
    int base = (blockIdx.x * 256 + threadIdx.x) * 8;
    const float* src;
    __bf16* dst;
    if (base < nEmb) {
        src = emb + base; dst = embb + base;
    } else {
        int j = base - nEmb;
        if (j >= D * TWO_D) return;
        src = W + j; dst = Wb + j;
    }
    float4 f0 = *(const float4*)(src);
    float4 f1 = *(const float4*)(src + 4);
    v8bf v;
    v[0] = (__bf16)f0.x; v[1] = (__bf16)f0.y; v[2] = (__bf16)f0.z; v[3] = (__bf16)f0.w;
    v[4] = (__bf16)f1.x; v[5] = (__bf16)f1.y; v[6] = (__bf16)f1.z; v[7] = (__bf16)f1.w;
    *(v8bf*)dst = v;
}

// ---------------------------------------------------------------------------
// Fused aggregation + MFMA node kernel. Block = 256 threads = 4 waves,
// covers 64 nodes.
//
// Phase 1 (aggregate): 16 groups of 16 lanes; group g handles nodes
// n0+g*4+j (j=0..3). Lane il of a group owns 8 dims (v8bf = 16 B) of the
// 128-dim row. Per edge: gather embb[col] (bf16), dot via 4-step width-16
// butterfly, exp, accumulate in fp32 regs. Result and the node's own embb
// row are written straight into the XOR-swizzled LDS x-tile as bf16
// (granule(m,q) at m*32 + (q ^ (m&7))) -- no global agg round trip.
//
// Phase 2 (GEMM+LN): round-3-verified 16x16x32 bf16 MFMA, D-tile layout
// col=lane&15 (feat), row=quad*4+reg (node); LN = 4-step shfl within wave.
// ---------------------------------------------------------------------------
__global__ __launch_bounds__(256) void gcn_fused(
    const __bf16* __restrict__ embb,
    const __bf16* __restrict__ Wb,
    const int* __restrict__ colidx,
    const int* __restrict__ rowstart,
    const int* __restrict__ deg,
    const float* __restrict__ bias,
    const float* __restrict__ gamma,
    const float* __restrict__ beta,
    float* __restrict__ out, int N)
{
    __shared__ __align__(16) __bf16 xt[64 * 256];   // 32 KB swizzled x-tile

    int t    = threadIdx.x;
    int wave = t >> 6;
    int lane = t & 63;
    int quad = lane >> 4;
    int il   = lane & 15;
    int n0   = blockIdx.x * 64;
    int grp  = wave * 4 + quad;      // 0..15

    // ---------------- phase 1: aggregate 4 nodes per group ----------------
    #pragma unroll
    for (int j = 0; j < 4; ++j) {
        int m = grp * 4 + j;         // local row 0..63
        int n = n0 + m;

        v8bf a8;
        float acc[8];
        #pragma unroll
        for (int q = 0; q < 8; ++q) acc[q] = 0.f;
        float den = 0.f;

        if (n < N) {
            a8 = *(const v8bf*)(embb + (size_t)n * D + il * 8);
            float af[8];
            #pragma unroll
            for (int q = 0; q < 8; ++q) af[q] = (float)a8[q];

            int e = rowstart[n], end = e + deg[n];
            for (; e + 1 < end; e += 2) {
                int c0 = colidx[e], c1 = colidx[e + 1];
                v8bf v0 = *(const v8bf*)(embb + (size_t)c0 * D + il * 8);
                v8bf v1 = *(const v8bf*)(embb + (size_t)c1 * D + il * 8);
                float vf0[8], vf1[8];
                float t0 = 0.f, t1 = 0.f;
                #pragma unroll
                for (int q = 0; q < 8; ++q) {
                    vf0[q] = (float)v0[q];
                    vf1[q] = (float)v1[q];
                    t0 += af[q] * vf0[q];
                    t1 += af[q] * vf1[q];
                }
                #pragma unroll
                for (int off = 1; off <= 8; off <<= 1) {
                    t0 += __shfl_xor(t0, off, 16);
                    t1 += __shfl_xor(t1, off, 16);
                }
                float w0 = __expf(t0), w1 = __expf(t1);
                #pragma unroll
                for (int q = 0; q < 8; ++q)
                    acc[q] += w0 * vf0[q] + w1 * vf1[q];
                den += w0 + w1;
            }
            if (e < end) {
                int c0 = colidx[e];
                v8bf v0 = *(const v8bf*)(embb + (size_t)c0 * D + il * 8);
                float vf0[8];
                float t0 = 0.f;
                #pragma unroll
                for (int q = 0; q < 8; ++q) {
                    vf0[q] = (float)v0[q];
                    t0 += af[q] * vf0[q];
                }
                #pragma unroll
                for (int off = 1; off <= 8; off <<= 1)
                    t0 += __shfl_xor(t0, off, 16);
                float w0 = __expf(t0);
                #pragma unroll
                for (int q = 0; q < 8; ++q) acc[q] += w0 * vf0[q];
                den += w0;
            }
        } else {
            #pragma unroll
            for (int q = 0; q < 8; ++q) a8[q] = (__bf16)0.0f;
        }

        float inv = 1.0f / (den + 1e-20f);   // deg==0 -> agg = 0 (matches ref)
        v8bf r;
        #pragma unroll
        for (int q = 0; q < 8; ++q) r[q] = (__bf16)(acc[q] * inv);

        // stage both halves of row m (swizzled granules)
        *(v8bf*)(xt + (m * 32 + (il        ^ (m & 7))) * 8) = a8;
        *(v8bf*)(xt + (m * 32 + ((16 + il) ^ (m & 7))) * 8) = r;
    }
    __syncthreads();

    // ---------------- phase 2: MFMA GEMM + LayerNorm ----------------
    int mrow = lane & 15;
    int mloc = wave * 16 + mrow;     // local node row this lane's A-frag uses

    v8bf a[8];
    #pragma unroll
    for (int kt = 0; kt < 8; ++kt) {
        int g = (kt * 4 + quad) ^ (mloc & 7);
        a[kt] = *(const v8bf*)(xt + (mloc * 32 + g) * 8);
    }

    float bi[8], gm[8], bt[8];
    #pragma unroll
    for (int ft = 0; ft < 8; ++ft) {
        int f = ft * 16 + mrow;
        bi[ft] = bias[f]; gm[ft] = gamma[f]; bt[ft] = beta[f];
    }

    v4f accf[8];
    #pragma unroll
    for (int ft = 0; ft < 8; ++ft)
        #pragma unroll
        for (int r = 0; r < 4; ++r) accf[ft][r] = 0.0f;

    #pragma unroll
    for (int kt = 0; kt < 8; ++kt) {
        #pragma unroll
        for (int ft = 0; ft < 8; ++ft) {
            v8bf b = *(const v8bf*)(Wb + (ft * 16 + mrow) * TWO_D + kt * 32 + quad * 8);
            accf[ft] = __builtin_amdgcn_mfma_f32_16x16x32_bf16(a[kt], b, accf[ft], 0, 0, 0);
        }
    }

    #pragma unroll
    for (int ft = 0; ft < 8; ++ft)
        #pragma unroll
        for (int r = 0; r < 4; ++r) accf[ft][r] += bi[ft];

    #pragma unroll
    for (int r = 0; r < 4; ++r) {
        float s = 0.f, s2 = 0.f;
        #pragma unroll
        for (int ft = 0; ft < 8; ++ft) {
            float x = accf[ft][r];
            s += x; s2 += x * x;
        }
        #pragma unroll
        for (int off = 1; off <= 8; off <<= 1) {
            s  += __shfl_xor(s,  off, 64);
            s2 += __shfl_xor(s2, off, 64);
        }
        float mu  = s * (1.0f / 128.0f);
        float var = s2 * (1.0f / 128.0f) - mu * mu;
        float ivn = rsqrtf(var + 1e-5f);
        int n = n0 + wave * 16 + quad * 4 + r;
        if (n < N) {
            #pragma unroll
            for (int ft = 0; ft < 8; ++ft) {
                int f = ft * 16 + mrow;
                out[(size_t)n * D + f] = (accf[ft][r] - mu) * ivn * gm[ft] + bt[ft];
            }
        }
    }
}

// ===========================================================================
// Tier B: round-3 kernels (fp32 emb), used if ws too small for embb
// ===========================================================================
__global__ __launch_bounds__(256) void k_wcvt(const float* __restrict__ W,
                                              __bf16* __restrict__ Wb) {
    int i = blockIdx.x * 256 + threadIdx.x;
    if (i < D * TWO_D) Wb[i] = (__bf16)W[i];
}

__global__ __launch_bounds__(256) void gcn_agg(const float* __restrict__ emb,
                                               const int* __restrict__ colidx,
                                               const int* __restrict__ rowstart,
                                               const int* __restrict__ deg,
                                               float* __restrict__ out, int N) {
    int n = blockIdx.x * 8 + (threadIdx.x >> 5);
    int l = threadIdx.x & 31;
    if (n >= N) return;
    const float4 a = *(const float4*)(emb + (size_t)n * D + l * 4);
    int e   = rowstart[n];
    int end = e + deg[n];
    float sx = 0.f, sy = 0.f, sz = 0.f, sw = 0.f, den = 0.f;
    for (; e + 1 < end; e += 2) {
        int c0 = colidx[e], c1 = colidx[e + 1];
        float4 v0 = *(const float4*)(emb + (size_t)c0 * D + l * 4);
        float4 v1 = *(const float4*)(emb + (size_t)c1 * D + l * 4);
        float t0 = a.x * v0.x + a.y * v0.y + a.z * v0.z + a.w * v0.w;
        float t1 = a.x * v1.x + a.y * v1.y + a.z * v1.z + a.w * v1.w;
        #pragma unroll
        for (int off = 16; off >= 1; off >>= 1) {
            t0 += __shfl_xor(t0, off, 32);
            t1 += __shfl_xor(t1, off, 32);
        }
        float w0 = __expf(t0), w1 = __expf(t1);
        sx += w0 * v0.x + w1 * v1.x;
        sy += w0 * v0.y + w1 * v1.y;
        sz += w0 * v0.z + w1 * v1.z;
        sw += w0 * v0.w + w1 * v1.w;
        den += w0 + w1;
    }
    if (e < end) {
        int c0 = colidx[e];
        float4 v0 = *(const float4*)(emb + (size_t)c0 * D + l * 4);
        float t0 = a.x * v0.x + a.y * v0.y + a.z * v0.z + a.w * v0.w;
        #pragma unroll
        for (int off = 16; off >= 1; off >>= 1)
            t0 += __shfl_xor(t0, off, 32);
        float w0 = __expf(t0);
        sx += w0 * v0.x; sy += w0 * v0.y; sz += w0 * v0.z; sw += w0 * v0.w;
        den += w0;
    }
    float inv = 1.0f / (den + 1e-20f);
    *(float4*)(out + (size_t)n * D + l * 4) =
        make_float4(sx * inv, sy * inv, sz * inv, sw * inv);
}

__global__ __launch_bounds__(256) void gcn_node_mfma(
    const float* __restrict__ emb,
    const __bf16* __restrict__ Wb,
    const float* __restrict__ bias,
    const float* __restrict__ gamma,
    const float* __restrict__ beta,
    float* __restrict__ out, int N)
{
    __shared__ __align__(16) __bf16 xt[64 * 256];
    int t    = threadIdx.x;
    int wave = t >> 6;
    int lane = t & 63;
    int n0   = blockIdx.x * 64;
    #pragma unroll
    for (int j = 0; j < 8; ++j) {
        int gf = j * 256 + t;
        int m  = gf >> 5;
        int g  = gf & 31;
        int n  = n0 + m;
        int k  = g * 8;
        v8bf v;
        if (n < N) {
            const float* src = (k < D) ? (emb + (size_t)n * D + k)
                                       : (out + (size_t)n * D + (k - D));
            float4 f0 = *(const float4*)(src);
            float4 f1 = *(const float4*)(src + 4);
            v[0] = (__bf16)f0.x; v[1] = (__bf16)f0.y;
            v[2] = (__bf16)f0.z; v[3] = (__bf16)f0.w;
            v[4] = (__bf16)f1.x; v[5] = (__bf16)f1.y;
            v[6] = (__bf16)f1.z; v[7] = (__bf16)f1.w;
        } else {
            #pragma unroll
            for (int q = 0; q < 8; ++q) v[q] = (__bf16)0.0f;
        }
        *(v8bf*)(xt + (m * 32 + (g ^ (m & 7))) * 8) = v;
    }
    __syncthreads();

    int mrow = lane & 15;
    int quad = lane >> 4;
    int mloc = wave * 16 + mrow;

    v8bf a[8];
    #pragma unroll
    for (int kt = 0; kt < 8; ++kt) {
        int g = (kt * 4 + quad) ^ (mloc & 7);
        a[kt] = *(const v8bf*)(xt + (mloc * 32 + g) * 8);
    }
    float bi[8], gm[8], bt[8];
    #pragma unroll
    for (int ft = 0; ft < 8; ++ft) {
        int f = ft * 16 + mrow;
        bi[ft] = bias[f]; gm[ft] = gamma[f]; bt[ft] = beta[f];
    }
    v4f acc[8];
    #pragma unroll
    for (int ft = 0; ft < 8; ++ft)
        #pragma unroll
        for (int r = 0; r < 4; ++r) acc[ft][r] = 0.0f;
    #pragma unroll
    for (int kt = 0; kt < 8; ++kt) {
        #pragma unroll
        for (int ft = 0; ft < 8; ++ft) {
            v8bf b = *(const v8bf*)(Wb + (ft * 16 + mrow) * TWO_D + kt * 32 + quad * 8);
            acc[ft] = __builtin_amdgcn_mfma_f32_16x16x32_bf16(a[kt], b, acc[ft], 0, 0, 0);
        }
    }
    #pragma unroll
    for (int ft = 0; ft < 8; ++ft)
        #pragma unroll
        for (int r = 0; r < 4; ++r) acc[ft][r] += bi[ft];
    #pragma unroll
    for (int r = 0; r < 4; ++r) {
        float s = 0.f, s2 = 0.f;
        #pragma unroll
        for (int ft = 0; ft < 8; ++ft) {
            float x = acc[ft][r];
            s += x; s2 += x * x;
        }
        #pragma unroll
        for (int off = 1; off <= 8; off <<= 1) {
            s  += __shfl_xor(s,  off, 64);
            s2 += __shfl_xor(s2, off, 64);
        }
        float mu  = s * (1.0f / 128.0f);
        float var = s2 * (1.0f / 128.0f) - mu * mu;
        float inv = rsqrtf(var + 1e-5f);
        int n = n0 + wave * 16 + quad * 4 + r;
        if (n < N) {
            #pragma unroll
            for (int ft = 0; ft < 8; ++ft) {
                int f = ft * 16 + mrow;
                out[(size_t)n * D + f] = (acc[ft][r] - mu) * inv * gm[ft] + bt[ft];
            }
        }
    }
}

// ===========================================================================
// Tier C: round-1 atomic fallback
// ===========================================================================
__global__ __launch_bounds__(256) void gcn_edge_attn(
    const float* __restrict__ emb, const int* __restrict__ edges,
    float* __restrict__ agg, float* __restrict__ denom, int E) {
    int e    = (int)((blockIdx.x * 256u + threadIdx.x) >> 6);
    int lane = threadIdx.x & 63;
    if (e >= E) return;
    int row = edges[e];
    int col = edges[E + e];
    const float2 a = *(const float2*)(emb + (size_t)row * D + lane * 2);
    const float2 c = *(const float2*)(emb + (size_t)col * D + lane * 2);
    float s = a.x * c.x + a.y * c.y;
    #pragma unroll
    for (int off = 32; off >= 1; off >>= 1) s += __shfl_xor(s, off, 64);
    float attn = expf(s);
    float* dst = agg + (size_t)row * D + lane * 2;
    unsafeAtomicAdd(dst,     attn * c.x);
    unsafeAtomicAdd(dst + 1, attn * c.y);
    if (lane == 0) unsafeAtomicAdd(denom + row, attn);
}

__global__ __launch_bounds__(256) void gcn_node_fallback(
    const float* __restrict__ emb, const float* __restrict__ W,
    const float* __restrict__ bias, const float* __restrict__ gamma,
    const float* __restrict__ beta, const float* __restrict__ denom,
    float* __restrict__ out, int N) {
    __shared__ float scat[2][TWO_D];
    __shared__ float sred[2][4];
    int tid  = threadIdx.x;
    int g    = tid >> 7;
    int o    = tid & 127;
    int lane = tid & 63;
    int wig  = (tid >> 6) & 1;
    for (int n0 = blockIdx.x * 2; n0 < N; n0 += gridDim.x * 2) {
        int n = n0 + g;
        bool act = (n < N);
        if (act) {
            float ev  = emb[(size_t)n * D + o];
            float inv = 1.0f / (denom[n] + 1e-20f);
            scat[g][o]     = ev;
            scat[g][D + o] = out[(size_t)n * D + o] * inv;
        }
        __syncthreads();
        float acc = 0.f;
        if (act) {
            const float4* wr = (const float4*)(W + (size_t)o * TWO_D);
            #pragma unroll 4
            for (int k4 = 0; k4 < TWO_D / 4; ++k4) {
                float4 w = wr[k4];
                float4 a = *(const float4*)(&scat[g][k4 * 4]);
                acc += w.x * a.x + w.y * a.y + w.z * a.z + w.w * a.w;
            }
            acc += bias[o];
        }
        float s = acc, s2 = acc * acc;
        #pragma unroll
        for (int off = 32; off >= 1; off >>= 1) {
            s  += __shfl_xor(s,  off, 64);
            s2 += __shfl_xor(s2, off, 64);
        }
        if (lane == 0) { sred[g][wig * 2] = s; sred[g][wig * 2 + 1] = s2; }
        __syncthreads();
        if (act) {
            float ts  = sred[g][0] + sred[g][2];
            float ts2 = sred[g][1] + sred[g][3];
            float mu  = ts * (1.0f / 128.0f);
            float var = ts2 * (1.0f / 128.0f) - mu * mu;
            float inv = rsqrtf(var + 1e-5f);
            out[(size_t)n * D + o] = (acc - mu) * inv * gamma[o] + beta[o];
        }
        __syncthreads();
    }
}

// ---------------------------------------------------------------------------
extern "C" void kernel_launch(void* const* d_in, const int* in_sizes, int n_in,
                              void* d_out, int out_size, void* d_ws, size_t ws_size,
                              hipStream_t stream) {
    const float* emb   = (const float*)d_in[0];
    const int*   edges = (const int*)  d_in[1];
    const float* W     = (const float*)d_in[2];
    const float* bias  = (const float*)d_in[3];
    const float* gamma = (const float*)d_in[4];
    const float* beta  = (const float*)d_in[5];
    float* out = (float*)d_out;

    int N = in_sizes[0] / D;        // 50000
    int E = in_sizes[1] / 2;        // 600000
    int nBlocks = (N + 255) / 256;  // 196 (scan2 requires <=256)
    int eBlocks = (E + 255) / 256;

    char* ws = (char*)d_ws;
    int*    deg      = (int*)   (ws + OFF_DEG);
    int*    part     = (int*)   (ws + OFF_PART);
    int*    btot     = (int*)   (ws + OFF_BTOT);
    int*    btots    = (int*)   (ws + OFF_BTOTS);
    int*    rowstart = (int*)   (ws + OFF_ROWSTART);
    int*    cursor   = (int*)   (ws + OFF_CURSOR);
    int*    colidx   = (int*)   (ws + OFF_COLIDX);
    __bf16* Wb       = (__bf16*)(ws + OFF_WBF16);
    __bf16* embb     = (__bf16*)(ws + OFF_EMBB);

    if (ws_size >= (size_t)WS_TIER_A && nBlocks <= 256) {
        int nEmb = N * D;
        int cvtThreads = (nEmb + D * TWO_D) / 8;
        hipMemsetAsync(deg, 0, (size_t)N * sizeof(int), stream);
        k_cvt    <<<(cvtThreads + 255) / 256, 256, 0, stream>>>(emb, W, embb, Wb, nEmb);
        k_hist   <<<eBlocks, 256, 0, stream>>>(edges, deg, E);
        k_scan1  <<<nBlocks, 256, 0, stream>>>(deg, part, btot, N);
        k_scan2  <<<1,       256, 0, stream>>>(btot, btots, nBlocks);
        k_initcur<<<nBlocks, 256, 0, stream>>>(part, btots, rowstart, cursor, N);
        k_scatter<<<eBlocks, 256, 0, stream>>>(edges, cursor, colidx, E);
        gcn_fused<<<(N + 63) / 64, 256, 0, stream>>>(embb, Wb, colidx, rowstart,
                                                     deg, bias, gamma, beta, out, N);
    } else if (ws_size >= (size_t)WS_TIER_B && nBlocks <= 256) {
        hipMemsetAsync(deg, 0, (size_t)N * sizeof(int), stream);
        k_wcvt   <<<(D * TWO_D + 255) / 256, 256, 0, stream>>>(W, Wb);
        k_hist   <<<eBlocks, 256, 0, stream>>>(edges, deg, E);
        k_scan1  <<<nBlocks, 256, 0, stream>>>(deg, part, btot, N);
        k_scan2  <<<1,       256, 0, stream>>>(btot, btots, nBlocks);
        k_initcur<<<nBlocks, 256, 0, stream>>>(part, btots, rowstart, cursor, N);
        k_scatter<<<eBlocks, 256, 0, stream>>>(edges, cursor, colidx, E);
        gcn_agg  <<<(N + 7) / 8, 256, 0, stream>>>(emb, colidx, rowstart, deg, out, N);
        gcn_node_mfma<<<(N + 63) / 64, 256, 0, stream>>>(emb, Wb, bias, gamma,
                                                         beta, out, N);
    } else {
        float* denom = (float*)d_ws;
        hipMemsetAsync(out,   0, (size_t)N * D * sizeof(float), stream);
        hipMemsetAsync(denom, 0, (size_t)N * sizeof(float), stream);
        gcn_edge_attn<<<(E + 3) / 4, 256, 0, stream>>>(emb, edges, out, denom, E);
        gcn_node_fallback<<<512, 256, 0, stream>>>(emb, W, bias, gamma, beta,
                                                   denom, out, N);
    }
}